// Round 1
// baseline (141.722 us; speedup 1.0000x reference)
//
#include <hip/hip_runtime.h>
#include <stdint.h>

// Problem constants
#define B 16
#define T 256
#define NP 2304           // H*W = 48*48
#define START 127         // start_idx = min(max(128-1,0), T-1)
#define CNTT 129          // number of averaged timesteps (127..255)
#define NBLK_PIX 9        // NP / 256
#define CHUNK 9           // NP / 256 elements per thread in per-batch block

typedef unsigned long long u64;
typedef unsigned int u32;

// K1: avg over timesteps, emit sortable key (float bits << 12) | pixel.
// Values are in (0,1) so positive-float bit patterns are order-preserving.
__global__ __launch_bounds__(256) void k1_avg_keys(const float* __restrict__ in,
                                                   u64* __restrict__ keys) {
    int b = blockIdx.x / NBLK_PIX;
    int chunk = blockIdx.x % NBLK_PIX;
    int n = chunk * 256 + threadIdx.x;
    const float* p = in + ((size_t)b * T + START) * NP + n;
    float s = 0.f;
#pragma unroll 4
    for (int t = 0; t < CNTT; ++t) s += p[(size_t)t * NP];
    float avg = s / (float)CNTT;
    u64 key = ((u64)__float_as_uint(avg) << 12) | (u32)n;
    keys[b * NP + n] = key;
}

// K2a: counting-rank sort. Each thread ranks one pixel against all N keys.
// Tie-break by pixel index (baked into key) => ranks form a permutation.
__global__ __launch_bounds__(256) void k2a_rank(const u64* __restrict__ keys,
                                                u64* __restrict__ sorted) {
    int b = blockIdx.x / NBLK_PIX;
    int chunk = blockIdx.x % NBLK_PIX;
    __shared__ u64 sk[NP];
    for (int i = threadIdx.x; i < NP; i += 256) sk[i] = keys[b * NP + i];
    __syncthreads();
    int p = chunk * 256 + threadIdx.x;
    u64 kp = sk[p];
    int cnt = 0;
#pragma unroll 8
    for (int q = 0; q < NP; ++q) cnt += (sk[q] < kp) ? 1 : 0;
    sorted[(size_t)b * NP + cnt] = kp;
}

// K2b: per-batch component labeling from sorted keys.
// break[i] = (v[i]-v[i-1]) > 0.1f ; comp = incl_scan(break)-1 ;
// minIdx[c] = min pixel index in comp c ; label[p] = minIdx[comp(p)] ;
// rank = (incl_scan(label[p]==p) - 1)[label[p]] -> row_of[p].
__global__ __launch_bounds__(256) void k2b_comp(const u64* __restrict__ sorted,
                                                int* __restrict__ row_of) {
    int b = blockIdx.x;
    int t = threadIdx.x;
    __shared__ u64 sk[NP];
    __shared__ int comp[NP];      // comp ids, later reused as cumrep
    __shared__ int minIdx[NP];
    __shared__ int labelArr[NP];
    __shared__ int scanbuf[256];

    const u64* kb = sorted + (size_t)b * NP;
    for (int i = t; i < NP; i += 256) sk[i] = kb[i];
    for (int i = t; i < NP; i += 256) minIdx[i] = 0x7fffffff;
    __syncthreads();

    int base = t * CHUNK;
    int loc[CHUNK];
    int s = 0;
    for (int j = 0; j < CHUNK; ++j) {
        int i = base + j;
        int br;
        if (i == 0) {
            br = 1;
        } else {
            float vi = __uint_as_float((u32)(sk[i] >> 12));
            float vm = __uint_as_float((u32)(sk[i - 1] >> 12));
            br = ((vi - vm) > 0.1f) ? 1 : 0;   // EPS = 1-0.9 rounds to 0.1f
        }
        s += br;
        loc[j] = s;  // inclusive within chunk
    }
    scanbuf[t] = s;
    __syncthreads();
    // Hillis-Steele inclusive scan over 256 partials
    for (int off = 1; off < 256; off <<= 1) {
        int v = scanbuf[t];
        int u = (t >= off) ? scanbuf[t - off] : 0;
        __syncthreads();
        scanbuf[t] = v + u;
        __syncthreads();
    }
    int exc = (t > 0) ? scanbuf[t - 1] : 0;
    for (int j = 0; j < CHUNK; ++j) comp[base + j] = exc + loc[j] - 1;
    __syncthreads();

    for (int j = 0; j < CHUNK; ++j) {
        int i = base + j;
        atomicMin(&minIdx[comp[i]], (int)(sk[i] & 0xFFFull));
    }
    __syncthreads();
    for (int j = 0; j < CHUNK; ++j) {
        int i = base + j;
        labelArr[(int)(sk[i] & 0xFFFull)] = minIdx[comp[i]];
    }
    __syncthreads();

    // representative scan over pixel indices
    int s2 = 0;
    int loc2[CHUNK];
    for (int j = 0; j < CHUNK; ++j) {
        int p2 = base + j;
        s2 += (labelArr[p2] == p2) ? 1 : 0;
        loc2[j] = s2;
    }
    scanbuf[t] = s2;
    __syncthreads();
    for (int off = 1; off < 256; off <<= 1) {
        int v = scanbuf[t];
        int u = (t >= off) ? scanbuf[t - off] : 0;
        __syncthreads();
        scanbuf[t] = v + u;
        __syncthreads();
    }
    int exc2 = (t > 0) ? scanbuf[t - 1] : 0;
    __syncthreads();
    for (int j = 0; j < CHUNK; ++j) comp[base + j] = exc2 + loc2[j];  // cumrep (inclusive)
    __syncthreads();

    int* ro = row_of + b * NP;
    for (int i = t; i < NP; i += 256) ro[i] = comp[labelArr[i]] - 1;
}

// K3: the big write. One block per output row (b, r); 576 threads x float4.
__global__ __launch_bounds__(576) void k3_write(const int* __restrict__ row_of,
                                                float* __restrict__ out) {
    int row = blockIdx.x;          // 0 .. B*NP-1
    int b = row / NP;
    int r = row - b * NP;
    const int4* rp = (const int4*)(row_of + b * NP);
    int4 rv = rp[threadIdx.x];
    float4 o;
    o.x = (rv.x == r) ? 1.f : 0.f;
    o.y = (rv.y == r) ? 1.f : 0.f;
    o.z = (rv.z == r) ? 1.f : 0.f;
    o.w = (rv.w == r) ? 1.f : 0.f;
    ((float4*)out)[(size_t)row * (NP / 4) + threadIdx.x] = o;
}

extern "C" void kernel_launch(void* const* d_in, const int* in_sizes, int n_in,
                              void* d_out, int out_size, void* d_ws, size_t ws_size,
                              hipStream_t stream) {
    const float* in = (const float*)d_in[0];
    float* out = (float*)d_out;
    char* ws = (char*)d_ws;
    // ws layout: keys [B*NP u64] | sorted [B*NP u64] | row_of [B*NP int]
    u64* keys   = (u64*)ws;                       // 294912 B
    u64* sorted = (u64*)(ws + 294912);            // 294912 B
    int* row_of = (int*)(ws + 589824);            // 147456 B (16B aligned)

    k1_avg_keys<<<B * NBLK_PIX, 256, 0, stream>>>(in, keys);
    k2a_rank<<<B * NBLK_PIX, 256, 0, stream>>>(keys, sorted);
    k2b_comp<<<B, 256, 0, stream>>>(sorted, row_of);
    k3_write<<<B * NP, 576, 0, stream>>>(row_of, out);
}

// Round 2
// 124.965 us; speedup vs baseline: 1.1341x; 1.1341x over previous
//
#include <hip/hip_runtime.h>
#include <stdint.h>

// Problem constants
#define B 16
#define T 256
#define NP 2304           // H*W = 48*48
#define START 127         // start_idx = min(max(128-1,0), T-1)
#define CNTT 129          // number of averaged timesteps (127..255)
#define NBLK_PIX 9        // NP / 256
#define CHUNK 9           // NP / 256 elements per thread in per-batch block
#define K3_ROWS 16        // output rows per k3 block

typedef unsigned long long u64;
typedef unsigned int u32;

// K1: avg over timesteps, emit sortable key (float bits << 12) | pixel.
// Values are in (0,1) so positive-float bit patterns are order-preserving.
__global__ __launch_bounds__(256) void k1_avg_keys(const float* __restrict__ in,
                                                   u64* __restrict__ keys) {
    int b = blockIdx.x / NBLK_PIX;
    int chunk = blockIdx.x % NBLK_PIX;
    int n = chunk * 256 + threadIdx.x;
    const float* p = in + ((size_t)b * T + START) * NP + n;
    float s0 = 0.f, s1 = 0.f, s2 = 0.f, s3 = 0.f;
    int t = 0;
#pragma unroll 4
    for (; t + 4 <= CNTT; t += 4) {
        s0 += p[(size_t)t * NP];
        s1 += p[(size_t)(t + 1) * NP];
        s2 += p[(size_t)(t + 2) * NP];
        s3 += p[(size_t)(t + 3) * NP];
    }
    for (; t < CNTT; ++t) s0 += p[(size_t)t * NP];
    float avg = ((s0 + s1) + (s2 + s3)) / (float)CNTT;
    u64 key = ((u64)__float_as_uint(avg) << 12) | (u32)n;
    keys[b * NP + n] = key;
}

// K2a: counting-rank sort. Each thread ranks one pixel against all N keys.
// Tie-break by pixel index (baked into key) => ranks form a permutation.
__global__ __launch_bounds__(256) void k2a_rank(const u64* __restrict__ keys,
                                                u64* __restrict__ sorted) {
    int b = blockIdx.x / NBLK_PIX;
    int chunk = blockIdx.x % NBLK_PIX;
    __shared__ u64 sk[NP];
    for (int i = threadIdx.x; i < NP; i += 256) sk[i] = keys[b * NP + i];
    __syncthreads();
    int p = chunk * 256 + threadIdx.x;
    u64 kp = sk[p];
    int c0 = 0, c1 = 0, c2 = 0, c3 = 0;
#pragma unroll 2
    for (int q = 0; q < NP; q += 4) {
        c0 += (sk[q]     < kp) ? 1 : 0;
        c1 += (sk[q + 1] < kp) ? 1 : 0;
        c2 += (sk[q + 2] < kp) ? 1 : 0;
        c3 += (sk[q + 3] < kp) ? 1 : 0;
    }
    int cnt = (c0 + c1) + (c2 + c3);
    sorted[(size_t)b * NP + cnt] = kp;
}

// K2b: per-batch component labeling from sorted keys.
// break[i] = (v[i]-v[i-1]) > 0.1f ; comp = incl_scan(break)-1 ;
// minIdx[c] = min pixel index in comp c ; label[p] = minIdx[comp(p)] ;
// rank = (incl_scan(label[p]==p) - 1)[label[p]] -> row_of[p].
__global__ __launch_bounds__(256) void k2b_comp(const u64* __restrict__ sorted,
                                                int* __restrict__ row_of) {
    int b = blockIdx.x;
    int t = threadIdx.x;
    __shared__ u64 sk[NP];
    __shared__ int comp[NP];      // comp ids, later reused as cumrep
    __shared__ int minIdx[NP];
    __shared__ int labelArr[NP];
    __shared__ int scanbuf[256];

    const u64* kb = sorted + (size_t)b * NP;
    for (int i = t; i < NP; i += 256) sk[i] = kb[i];
    for (int i = t; i < NP; i += 256) minIdx[i] = 0x7fffffff;
    __syncthreads();

    int base = t * CHUNK;
    int loc[CHUNK];
    int s = 0;
    for (int j = 0; j < CHUNK; ++j) {
        int i = base + j;
        int br;
        if (i == 0) {
            br = 1;
        } else {
            float vi = __uint_as_float((u32)(sk[i] >> 12));
            float vm = __uint_as_float((u32)(sk[i - 1] >> 12));
            br = ((vi - vm) > 0.1f) ? 1 : 0;   // EPS = 1-0.9 rounds to 0.1f
        }
        s += br;
        loc[j] = s;  // inclusive within chunk
    }
    scanbuf[t] = s;
    __syncthreads();
    // Hillis-Steele inclusive scan over 256 partials
    for (int off = 1; off < 256; off <<= 1) {
        int v = scanbuf[t];
        int u = (t >= off) ? scanbuf[t - off] : 0;
        __syncthreads();
        scanbuf[t] = v + u;
        __syncthreads();
    }
    int exc = (t > 0) ? scanbuf[t - 1] : 0;
    for (int j = 0; j < CHUNK; ++j) comp[base + j] = exc + loc[j] - 1;
    __syncthreads();

    // per-thread run-coalesced atomicMin (cuts same-address contention ~9x)
    {
        int curComp = comp[base];
        int curMin = (int)(sk[base] & 0xFFFull);
        for (int j = 1; j < CHUNK; ++j) {
            int i = base + j;
            int c = comp[i];
            int idx = (int)(sk[i] & 0xFFFull);
            if (c == curComp) {
                curMin = min(curMin, idx);
            } else {
                atomicMin(&minIdx[curComp], curMin);
                curComp = c;
                curMin = idx;
            }
        }
        atomicMin(&minIdx[curComp], curMin);
    }
    __syncthreads();
    for (int j = 0; j < CHUNK; ++j) {
        int i = base + j;
        labelArr[(int)(sk[i] & 0xFFFull)] = minIdx[comp[i]];
    }
    __syncthreads();

    // representative scan over pixel indices
    int s2 = 0;
    int loc2[CHUNK];
    for (int j = 0; j < CHUNK; ++j) {
        int p2 = base + j;
        s2 += (labelArr[p2] == p2) ? 1 : 0;
        loc2[j] = s2;
    }
    scanbuf[t] = s2;
    __syncthreads();
    for (int off = 1; off < 256; off <<= 1) {
        int v = scanbuf[t];
        int u = (t >= off) ? scanbuf[t - off] : 0;
        __syncthreads();
        scanbuf[t] = v + u;
        __syncthreads();
    }
    int exc2 = (t > 0) ? scanbuf[t - 1] : 0;
    __syncthreads();
    for (int j = 0; j < CHUNK; ++j) comp[base + j] = exc2 + loc2[j];  // cumrep (inclusive)
    __syncthreads();

    int* ro = row_of + b * NP;
    for (int i = t; i < NP; i += 256) ro[i] = comp[labelArr[i]] - 1;
}

// K3: the big write. One block per K3_ROWS output rows; one int4 row_of read
// amortized over K3_ROWS float4 stores per thread.
__global__ __launch_bounds__(576) void k3_write(const int* __restrict__ row_of,
                                                float* __restrict__ out) {
    const int rowBlocks = NP / K3_ROWS;          // 144 blocks per batch
    int blk = blockIdx.x;                        // 0 .. B*rowBlocks-1
    int b = blk / rowBlocks;
    int r0 = (blk - b * rowBlocks) * K3_ROWS;
    const int4* rp = (const int4*)(row_of + b * NP);
    int4 rv = rp[threadIdx.x];
    float4* ob = (float4*)out + (size_t)(b * NP + r0) * (NP / 4) + threadIdx.x;
#pragma unroll
    for (int k = 0; k < K3_ROWS; ++k) {
        int r = r0 + k;
        float4 o;
        o.x = (rv.x == r) ? 1.f : 0.f;
        o.y = (rv.y == r) ? 1.f : 0.f;
        o.z = (rv.z == r) ? 1.f : 0.f;
        o.w = (rv.w == r) ? 1.f : 0.f;
        ob[(size_t)k * (NP / 4)] = o;
    }
}

extern "C" void kernel_launch(void* const* d_in, const int* in_sizes, int n_in,
                              void* d_out, int out_size, void* d_ws, size_t ws_size,
                              hipStream_t stream) {
    const float* in = (const float*)d_in[0];
    float* out = (float*)d_out;
    char* ws = (char*)d_ws;
    // ws layout: keys [B*NP u64] | sorted [B*NP u64] | row_of [B*NP int]
    u64* keys   = (u64*)ws;                       // 294912 B
    u64* sorted = (u64*)(ws + 294912);            // 294912 B
    int* row_of = (int*)(ws + 589824);            // 147456 B (16B aligned)

    k1_avg_keys<<<B * NBLK_PIX, 256, 0, stream>>>(in, keys);
    k2a_rank<<<B * NBLK_PIX, 256, 0, stream>>>(keys, sorted);
    k2b_comp<<<B, 256, 0, stream>>>(sorted, row_of);
    k3_write<<<B * NP / K3_ROWS, 576, 0, stream>>>(row_of, out);
}

// Round 3
// 85.783 us; speedup vs baseline: 1.6521x; 1.4568x over previous
//
#include <hip/hip_runtime.h>
#include <stdint.h>

// Problem constants
#define B 16
#define T 256
#define NP 2304           // H*W = 48*48
#define START 127         // start_idx = min(max(128-1,0), T-1)
#define NCOL 576          // NP/4 float4 columns per batch
#define TSPLIT 4          // time-range split for kA partials (33,32,32,32)
#define K3_ROWS 16        // output rows per k3 block
#define NBINS 21          // bins of width 0.05 over (0,1); +clamp catches rounding to 20
#define BINW 20.0f

typedef unsigned int u32;

__device__ inline float4 f4add(float4 x, float4 y) {
    return make_float4(x.x + y.x, x.y + y.y, x.z + y.z, x.w + y.w);
}

// Kernel A: partial time sums. Grid 144x256; task = (batch, t-quarter, float4 col).
__global__ __launch_bounds__(256) void kA_partial(const float* __restrict__ in,
                                                  float4* __restrict__ part) {
    int gid = blockIdx.x * 256 + threadIdx.x;        // 0..36863
    int b   = gid / (TSPLIT * NCOL);
    int rem = gid - b * (TSPLIT * NCOL);
    int q   = rem / NCOL;
    int col = rem - q * NCOL;
    int t0  = (q == 0) ? START : (START + 33 + 32 * (q - 1));  // 127,160,192,224
    int nt  = (q == 0) ? 33 : 32;
    const float4* p = (const float4*)(in + ((size_t)b * T + t0) * NP) + col;
    float4 z = make_float4(0.f, 0.f, 0.f, 0.f);
    float4 a0 = z, a1 = z, a2 = z, a3 = z, a4 = z, a5 = z, a6 = z, a7 = z;
    int t = 0;
    for (; t + 8 <= nt; t += 8) {
        a0 = f4add(a0, p[(size_t)(t + 0) * NCOL]);
        a1 = f4add(a1, p[(size_t)(t + 1) * NCOL]);
        a2 = f4add(a2, p[(size_t)(t + 2) * NCOL]);
        a3 = f4add(a3, p[(size_t)(t + 3) * NCOL]);
        a4 = f4add(a4, p[(size_t)(t + 4) * NCOL]);
        a5 = f4add(a5, p[(size_t)(t + 5) * NCOL]);
        a6 = f4add(a6, p[(size_t)(t + 6) * NCOL]);
        a7 = f4add(a7, p[(size_t)(t + 7) * NCOL]);
    }
    for (; t < nt; ++t) a0 = f4add(a0, p[(size_t)t * NCOL]);
    float4 s = f4add(f4add(f4add(a0, a1), f4add(a2, a3)),
                     f4add(f4add(a4, a5), f4add(a6, a7)));
    part[(b * TSPLIT + q) * NCOL + col] = s;
}

// Kernel B: per-batch histogram clustering -> row_of.
// Bin width 0.05 < EPS: within-bin pairs always connected; sorted-adjacent pair
// across occupied bins = (maxV[prevOcc], minV[nextOcc]); break iff gap > 0.1f
// (identical f32 arithmetic to the reference's sorted-gap test).
__global__ __launch_bounds__(256) void kB_rows(const float* __restrict__ partF,
                                               int* __restrict__ row_of) {
    int b = blockIdx.x;
    int tid = threadIdx.x;
    __shared__ u32 binMinV[NBINS], binMaxV[NBINS], binMinI[NBINS];
    __shared__ int binRow[NBINS];
    __shared__ int compOfBin[NBINS];
    __shared__ u32 compMinI[NBINS];
    __shared__ unsigned char binOf[NP];

    if (tid < NBINS) {
        binMinV[tid] = 0xFFFFFFFFu;
        binMaxV[tid] = 0u;
        binMinI[tid] = 0xFFFFFFFFu;
    }
    __syncthreads();

    const float* p0 = partF + (size_t)(b * TSPLIT + 0) * NP;
    const float* p1 = partF + (size_t)(b * TSPLIT + 1) * NP;
    const float* p2 = partF + (size_t)(b * TSPLIT + 2) * NP;
    const float* p3 = partF + (size_t)(b * TSPLIT + 3) * NP;

    // per-thread run-merged atomic updates (few hot bins -> runs are common)
    int curBin = -1;
    u32 cMin = 0, cMax = 0, cIdx = 0;
    for (int p = tid; p < NP; p += 256) {
        float s = (p0[p] + p1[p]) + (p2[p] + p3[p]);
        float avg = s / 129.0f;                     // exact IEEE div, off critical path
        int bin = (int)(avg * BINW);
        bin = bin < 0 ? 0 : (bin > NBINS - 1 ? NBINS - 1 : bin);
        binOf[p] = (unsigned char)bin;
        u32 vb = __float_as_uint(avg);              // positive floats: bits order-preserving
        if (bin == curBin) {
            cMin = min(cMin, vb);
            cMax = max(cMax, vb);
            cIdx = min(cIdx, (u32)p);
        } else {
            if (curBin >= 0) {
                atomicMin(&binMinV[curBin], cMin);
                atomicMax(&binMaxV[curBin], cMax);
                atomicMin(&binMinI[curBin], cIdx);
            }
            curBin = bin; cMin = vb; cMax = vb; cIdx = (u32)p;
        }
    }
    if (curBin >= 0) {
        atomicMin(&binMinV[curBin], cMin);
        atomicMax(&binMaxV[curBin], cMax);
        atomicMin(&binMinI[curBin], cIdx);
    }
    __syncthreads();

    if (tid == 0) {
        // merge consecutive occupied bins into components
        int K = 0, prev = -1;
        for (int bn = 0; bn < NBINS; ++bn) {
            if (binMinI[bn] == 0xFFFFFFFFu) continue;
            bool newc;
            if (prev < 0) {
                newc = true;
            } else {
                float gap = __uint_as_float(binMinV[bn]) - __uint_as_float(binMaxV[prev]);
                newc = (gap > 0.1f);                // EPS rounds to 0.1f in f32
            }
            if (newc) {
                compMinI[K] = binMinI[bn];
                ++K;
            } else {
                compMinI[K - 1] = min(compMinI[K - 1], binMinI[bn]);
            }
            compOfBin[bn] = K - 1;
            prev = bn;
        }
        // rank components by smallest pixel index (reference discovery order)
        for (int bn = 0; bn < NBINS; ++bn) {
            if (binMinI[bn] == 0xFFFFFFFFu) { binRow[bn] = 0; continue; }
            u32 mi = compMinI[compOfBin[bn]];
            int r = 0;
            for (int c = 0; c < K; ++c) r += (compMinI[c] < mi) ? 1 : 0;
            binRow[bn] = r;
        }
    }
    __syncthreads();

    int* ro = row_of + b * NP;
    for (int p = tid; p < NP; p += 256) ro[p] = binRow[binOf[p]];
}

// K3: the big write. One block per K3_ROWS output rows; one int4 row_of read
// amortized over K3_ROWS float4 stores per thread.
__global__ __launch_bounds__(576) void k3_write(const int* __restrict__ row_of,
                                                float* __restrict__ out) {
    const int rowBlocks = NP / K3_ROWS;          // 144 blocks per batch
    int blk = blockIdx.x;                        // 0 .. B*rowBlocks-1
    int b = blk / rowBlocks;
    int r0 = (blk - b * rowBlocks) * K3_ROWS;
    const int4* rp = (const int4*)(row_of + b * NP);
    int4 rv = rp[threadIdx.x];
    float4* ob = (float4*)out + (size_t)(b * NP + r0) * (NP / 4) + threadIdx.x;
#pragma unroll
    for (int k = 0; k < K3_ROWS; ++k) {
        int r = r0 + k;
        float4 o;
        o.x = (rv.x == r) ? 1.f : 0.f;
        o.y = (rv.y == r) ? 1.f : 0.f;
        o.z = (rv.z == r) ? 1.f : 0.f;
        o.w = (rv.w == r) ? 1.f : 0.f;
        ob[(size_t)k * (NP / 4)] = o;
    }
}

extern "C" void kernel_launch(void* const* d_in, const int* in_sizes, int n_in,
                              void* d_out, int out_size, void* d_ws, size_t ws_size,
                              hipStream_t stream) {
    const float* in = (const float*)d_in[0];
    float* out = (float*)d_out;
    char* ws = (char*)d_ws;
    // ws layout: part [B*TSPLIT*NCOL float4 = 589824 B] | row_of [B*NP int = 147456 B]
    float4* part = (float4*)ws;
    int* row_of  = (int*)(ws + 589824);

    kA_partial<<<(B * TSPLIT * NCOL) / 256, 256, 0, stream>>>(in, part);
    kB_rows<<<B, 256, 0, stream>>>((const float*)part, row_of);
    k3_write<<<B * NP / K3_ROWS, 576, 0, stream>>>(row_of, out);
}

// Round 4
// 77.492 us; speedup vs baseline: 1.8288x; 1.1070x over previous
//
#include <hip/hip_runtime.h>
#include <stdint.h>

// Problem constants
#define B 16
#define T 256
#define NP 2304           // H*W = 48*48
#define START 127         // start_idx = min(max(128-1,0), T-1)
#define NCOL 576          // NP/4 float4 columns per batch
#define TS 8              // time splits: 17 + 7*16 = 129 steps
#define NBINS 21          // bins of width 0.05 over (0,1); clamp catches edge rounding
#define BINW 20.0f

typedef unsigned int u32;

__device__ inline float4 f4add(float4 x, float4 y) {
    return make_float4(x.x + y.x, x.y + y.y, x.z + y.z, x.w + y.w);
}

// Kernel A: partial time sums. Grid 288x256; task = (batch, t-eighth, float4 col).
__global__ __launch_bounds__(256) void kA_partial(const float* __restrict__ in,
                                                  float4* __restrict__ part) {
    int gid = blockIdx.x * 256 + threadIdx.x;        // 0..73727
    int b   = gid / (TS * NCOL);
    int rem = gid - b * (TS * NCOL);
    int q   = rem / NCOL;
    int col = rem - q * NCOL;
    int t0  = (q == 0) ? START : (START + 17 + 16 * (q - 1));  // 127,144,160,...,240
    int nt  = (q == 0) ? 17 : 16;
    const float4* p = (const float4*)(in + ((size_t)b * T + t0) * NP) + col;
    float4 z = make_float4(0.f, 0.f, 0.f, 0.f);
    float4 a0 = z, a1 = z, a2 = z, a3 = z, a4 = z, a5 = z, a6 = z, a7 = z;
    int t = 0;
    for (; t + 8 <= nt; t += 8) {
        a0 = f4add(a0, p[(size_t)(t + 0) * NCOL]);
        a1 = f4add(a1, p[(size_t)(t + 1) * NCOL]);
        a2 = f4add(a2, p[(size_t)(t + 2) * NCOL]);
        a3 = f4add(a3, p[(size_t)(t + 3) * NCOL]);
        a4 = f4add(a4, p[(size_t)(t + 4) * NCOL]);
        a5 = f4add(a5, p[(size_t)(t + 5) * NCOL]);
        a6 = f4add(a6, p[(size_t)(t + 6) * NCOL]);
        a7 = f4add(a7, p[(size_t)(t + 7) * NCOL]);
    }
    for (; t < nt; ++t) a0 = f4add(a0, p[(size_t)t * NCOL]);
    float4 s = f4add(f4add(f4add(a0, a1), f4add(a2, a3)),
                     f4add(f4add(a4, a5), f4add(a6, a7)));
    part[(b * TS + q) * NCOL + col] = s;
}

// Kernel B: per-batch histogram clustering -> row_of.
// Bin width 0.05 < EPS: within-bin pairs always connected; the only candidate
// break is between (max of lower occupied bin, min of next occupied bin),
// tested with the same f32 compare (gap > 0.1f) as the reference's sorted scan.
__global__ __launch_bounds__(256) void kB_rows(const float* __restrict__ partF,
                                               int* __restrict__ row_of) {
    int b = blockIdx.x;
    int tid = threadIdx.x;
    __shared__ u32 binMinV[NBINS], binMaxV[NBINS], binMinI[NBINS];
    __shared__ int binRow[NBINS];
    __shared__ int compOfBin[NBINS];
    __shared__ u32 compMinI[NBINS];
    __shared__ unsigned char binOf[NP];

    if (tid < NBINS) {
        binMinV[tid] = 0xFFFFFFFFu;
        binMaxV[tid] = 0u;
        binMinI[tid] = 0xFFFFFFFFu;
    }
    __syncthreads();

    const float* pb = partF + (size_t)b * TS * NP;

    // per-thread run-merged atomic updates (few hot bins -> runs are common)
    int curBin = -1;
    u32 cMin = 0, cMax = 0, cIdx = 0;
    for (int p = tid; p < NP; p += 256) {
        float s0 = pb[0 * NP + p], s1 = pb[1 * NP + p];
        float s2 = pb[2 * NP + p], s3 = pb[3 * NP + p];
        float s4 = pb[4 * NP + p], s5 = pb[5 * NP + p];
        float s6 = pb[6 * NP + p], s7 = pb[7 * NP + p];
        float s = ((s0 + s1) + (s2 + s3)) + ((s4 + s5) + (s6 + s7));
        float avg = s / 129.0f;
        int bin = (int)(avg * BINW);
        bin = bin < 0 ? 0 : (bin > NBINS - 1 ? NBINS - 1 : bin);
        binOf[p] = (unsigned char)bin;
        u32 vb = __float_as_uint(avg);              // positive floats: bits order-preserving
        if (bin == curBin) {
            cMin = min(cMin, vb);
            cMax = max(cMax, vb);
            cIdx = min(cIdx, (u32)p);
        } else {
            if (curBin >= 0) {
                atomicMin(&binMinV[curBin], cMin);
                atomicMax(&binMaxV[curBin], cMax);
                atomicMin(&binMinI[curBin], cIdx);
            }
            curBin = bin; cMin = vb; cMax = vb; cIdx = (u32)p;
        }
    }
    if (curBin >= 0) {
        atomicMin(&binMinV[curBin], cMin);
        atomicMax(&binMaxV[curBin], cMax);
        atomicMin(&binMinI[curBin], cIdx);
    }
    __syncthreads();

    if (tid == 0) {
        // merge consecutive occupied bins into components
        int K = 0, prev = -1;
        for (int bn = 0; bn < NBINS; ++bn) {
            if (binMinI[bn] == 0xFFFFFFFFu) continue;
            bool newc;
            if (prev < 0) {
                newc = true;
            } else {
                float gap = __uint_as_float(binMinV[bn]) - __uint_as_float(binMaxV[prev]);
                newc = (gap > 0.1f);                // EPS = 1-0.9 rounds to 0.1f
            }
            if (newc) {
                compMinI[K] = binMinI[bn];
                ++K;
            } else {
                compMinI[K - 1] = min(compMinI[K - 1], binMinI[bn]);
            }
            compOfBin[bn] = K - 1;
            prev = bn;
        }
        // rank components by smallest pixel index (reference discovery order)
        for (int bn = 0; bn < NBINS; ++bn) {
            if (binMinI[bn] == 0xFFFFFFFFu) { binRow[bn] = 0; continue; }
            u32 mi = compMinI[compOfBin[bn]];
            int r = 0;
            for (int c = 0; c < K; ++c) r += (compMinI[c] < mi) ? 1 : 0;
            binRow[bn] = r;
        }
    }
    __syncthreads();

    int* ro = row_of + b * NP;
    for (int p = tid; p < NP; p += 256) ro[p] = binRow[binOf[p]];
}

// Kernel S: scatter the exactly B*NP ones into the zeroed output.
// Consecutive p within a wave usually share a row -> coalesced 256B stores.
__global__ __launch_bounds__(256) void kScatter(const int* __restrict__ row_of,
                                                float* __restrict__ out) {
    int gid = blockIdx.x * 256 + threadIdx.x;    // 0..36863
    int b = gid / NP;
    int p = gid - b * NP;
    int r = row_of[gid];
    out[(size_t)b * NP * NP + (size_t)r * NP + p] = 1.0f;
}

extern "C" void kernel_launch(void* const* d_in, const int* in_sizes, int n_in,
                              void* d_out, int out_size, void* d_ws, size_t ws_size,
                              hipStream_t stream) {
    const float* in = (const float*)d_in[0];
    float* out = (float*)d_out;
    char* ws = (char*)d_ws;
    // ws layout: part [B*TS*NCOL float4 = 1179648 B] | row_of [B*NP int = 147456 B]
    float4* part = (float4*)ws;
    int* row_of  = (int*)(ws + 1179648);

    kA_partial<<<(B * TS * NCOL) / 256, 256, 0, stream>>>(in, part);
    kB_rows<<<B, 256, 0, stream>>>((const float*)part, row_of);
    hipMemsetAsync(d_out, 0, (size_t)out_size * sizeof(float), stream);
    kScatter<<<(B * NP) / 256, 256, 0, stream>>>(row_of, out);
}